// Round 4
// baseline (543.830 us; speedup 1.0000x reference)
//
#include <hip/hip_runtime.h>
#include <cstdint>

// Instant-NGP hash-grid embedder, 2-phase with level->XCD affinity.
//
// Phase A: one block = one level x 512 points (2 pts/thread for MLP).
//   blockIdx%8 pins level pairs (i, 15-i) to one XCD residue (verified R2:
//   FETCH 1.56GB -> 149MB), coarse phase first then fine, so each XCD's 4MB
//   L2 holds exactly the active level slab. ws written with NON-TEMPORAL
//   stores so the 134MB stream doesn't evict the table slab from L2
//   (R2 FETCH was ~2x table size = eviction evidence).
// Phase B: streaming transpose ws[l][b] -> out[b][f*16+l]; 2 points/thread,
//   16B nt loads + nt stores (zero-reuse streaming).
//
// NOTE: __builtin_nontemporal_* requires NATIVE vector types — HIP's
// float2/float4 classes are rejected (R3 compile failure). Use
// ext_vector_type.
//
// Discrete steps (bottom_left trunc) replicated in float64 to match the
// NumPy reference under NEP-50 promotion. Resolutions hardcoded to the
// exact-math floor(16 * 2^(l/3)) values.

constexpr int NLEV = 16;
constexpr uint32_t HM_MASK = (1u << 19) - 1;

typedef float v2f __attribute__((ext_vector_type(2)));
typedef float v4f __attribute__((ext_vector_type(4)));

__device__ __constant__ double c_res[NLEV] = {
    16.0, 20.0, 25.0, 32.0, 40.0, 50.0, 64.0, 80.0,
    101.0, 128.0, 161.0, 203.0, 256.0, 322.0, 406.0, 512.0
};

__device__ __forceinline__ void ngp_eval_point(
    int b, int lev,
    const float* __restrict__ x,
    const v2f* __restrict__ tab2,
    float bm0, float bm1, float bm2,
    float d0, float d1, float d2,
    float& f0, float& f1)
{
    const float fx0 = x[3 * b + 0];
    const float fx1 = x[3 * b + 1];
    const float fx2 = x[3 * b + 2];

    const double res = c_res[lev];
    const double g0 = (double)d0 / res;
    const double g1 = (double)d1 / res;
    const double g2 = (double)d2 / res;
    const double q0 = (double)(fx0 - bm0) / g0;
    const double q1 = (double)(fx1 - bm1) / g1;
    const double q2 = (double)(fx2 - bm2) / g2;
    const int i0 = (int)q0;
    const int i1 = (int)q1;
    const int i2 = (int)q2;
    const float w0 = (float)(q0 - (double)i0);
    const float w1 = (float)(q1 - (double)i1);
    const float w2 = (float)(q2 - (double)i2);

    const uint32_t P1 = 2654435761u, P2 = 805459861u;
    const uint32_t h0a = (uint32_t)i0;
    const uint32_t h0b = h0a + 1u;
    const uint32_t h1a = (uint32_t)i1 * P1;
    const uint32_t h1b = h1a + P1;
    const uint32_t h2a = (uint32_t)i2 * P2;
    const uint32_t h2b = h2a + P2;
    const uint32_t base = (uint32_t)lev << 19;

    const v2f v000 = tab2[base + ((h0a ^ h1a ^ h2a) & HM_MASK)];
    const v2f v001 = tab2[base + ((h0a ^ h1a ^ h2b) & HM_MASK)];
    const v2f v010 = tab2[base + ((h0a ^ h1b ^ h2a) & HM_MASK)];
    const v2f v011 = tab2[base + ((h0a ^ h1b ^ h2b) & HM_MASK)];
    const v2f v100 = tab2[base + ((h0b ^ h1a ^ h2a) & HM_MASK)];
    const v2f v101 = tab2[base + ((h0b ^ h1a ^ h2b) & HM_MASK)];
    const v2f v110 = tab2[base + ((h0b ^ h1b ^ h2a) & HM_MASK)];
    const v2f v111 = tab2[base + ((h0b ^ h1b ^ h2b) & HM_MASK)];

    const float u0 = 1.0f - w0, u1 = 1.0f - w1, u2 = 1.0f - w2;
    const float waa = u1 * u2;
    const float wab = u1 * w2;
    const float wba = w1 * u2;
    const float wbb = w1 * w2;

    f0 = u0 * (waa * v000.x + wab * v001.x + wba * v010.x + wbb * v011.x)
       + w0 * (waa * v100.x + wab * v101.x + wba * v110.x + wbb * v111.x);
    f1 = u0 * (waa * v000.y + wab * v001.y + wba * v010.y + wbb * v011.y)
       + w0 * (waa * v100.y + wab * v101.y + wba * v110.y + wbb * v111.y);
}

// ---------------- Phase A: per-level gather+interp, level-major ws ----------
__global__ __launch_bounds__(256)
void ngp_levels_kernel(const float* __restrict__ x,
                       const float* __restrict__ table,
                       const float* __restrict__ box_min,
                       const float* __restrict__ box_max,
                       v2f* __restrict__ ws,
                       int B, int chunks)
{
    // XCD-affinity: residue = blockIdx%8 -> XCD (HW round-robin dispatch).
    // XCD residue i: level i (phase 1, coarse) then 15-i (phase 2, fine).
    const int xcd = blockIdx.x & 7;
    const int s   = blockIdx.x >> 3;
    const int lev   = (s < chunks) ? xcd : (15 - xcd);
    const int chunk = (s < chunks) ? s : (s - chunks);
    const int b0 = chunk * 512 + threadIdx.x;   // 2 points/thread, 256 apart
    const int b1 = b0 + 256;

    const float bm0 = box_min[0], bm1 = box_min[1], bm2 = box_min[2];
    const float d0 = box_max[0] - bm0;
    const float d1 = box_max[1] - bm1;
    const float d2 = box_max[2] - bm2;
    const v2f* tab2 = (const v2f*)table;

    if (b0 < B) {
        float f0, f1;
        ngp_eval_point(b0, lev, x, tab2, bm0, bm1, bm2, d0, d1, d2, f0, f1);
        // non-temporal: don't evict the table slab from this XCD's L2
        v2f r; r.x = f0; r.y = f1;
        __builtin_nontemporal_store(r, &ws[(size_t)lev * B + b0]);
    }
    if (b1 < B) {
        float f0, f1;
        ngp_eval_point(b1, lev, x, tab2, bm0, bm1, bm2, d0, d1, d2, f0, f1);
        v2f r; r.x = f0; r.y = f1;
        __builtin_nontemporal_store(r, &ws[(size_t)lev * B + b1]);
    }
}

// ---------------- Phase B: transpose ws[l][b] -> out[b][f*16+l] -------------
// 2 points per thread: one 16B load per level covers both points' float2.
__global__ __launch_bounds__(256)
void ngp_transpose_kernel(const v4f* __restrict__ ws4,
                          float* __restrict__ out,
                          int B)
{
    const int t = blockIdx.x * 256 + threadIdx.x;   // pair index
    const int b0 = 2 * t;
    if (b0 >= B) return;
    const int Bq = B >> 1;   // v4f elements per level row

    v4f v[NLEV];
#pragma unroll
    for (int l = 0; l < NLEV; ++l)
        v[l] = __builtin_nontemporal_load(&ws4[(size_t)l * Bq + t]);

    // point b0: (v.x, v.y) ; point b0+1: (v.z, v.w)
    v4f* o0 = (v4f*)(out + (size_t)b0 * 32);
#pragma unroll
    for (int i = 0; i < 4; ++i) {
        v4f a; a.x = v[4*i].x; a.y = v[4*i+1].x; a.z = v[4*i+2].x; a.w = v[4*i+3].x;
        __builtin_nontemporal_store(a, &o0[i]);
        v4f c; c.x = v[4*i].y; c.y = v[4*i+1].y; c.z = v[4*i+2].y; c.w = v[4*i+3].y;
        __builtin_nontemporal_store(c, &o0[4 + i]);
    }
    if (b0 + 1 < B) {
        v4f* o1 = (v4f*)(out + (size_t)(b0 + 1) * 32);
#pragma unroll
        for (int i = 0; i < 4; ++i) {
            v4f a; a.x = v[4*i].z; a.y = v[4*i+1].z; a.z = v[4*i+2].z; a.w = v[4*i+3].z;
            __builtin_nontemporal_store(a, &o1[i]);
            v4f c; c.x = v[4*i].w; c.y = v[4*i+1].w; c.z = v[4*i+2].w; c.w = v[4*i+3].w;
            __builtin_nontemporal_store(c, &o1[4 + i]);
        }
    }
}

// ---------------- Fallback: fused kernel (if ws too small) ------------------
__global__ __launch_bounds__(256)
void ngp_embed_fused_kernel(const float* __restrict__ x,
                            const float* __restrict__ table,
                            const float* __restrict__ box_min,
                            const float* __restrict__ box_max,
                            float* __restrict__ out,
                            int B)
{
    const int gid = blockIdx.x * 256 + threadIdx.x;
    const int b = gid >> 4;
    const int l = gid & 15;
    if (b >= B) return;

    const float bm0 = box_min[0], bm1 = box_min[1], bm2 = box_min[2];
    const float d0 = box_max[0] - bm0;
    const float d1 = box_max[1] - bm1;
    const float d2 = box_max[2] - bm2;

    float f0, f1;
    ngp_eval_point(b, l, x, (const v2f*)table,
                   bm0, bm1, bm2, d0, d1, d2, f0, f1);

    out[b * 32 + l]      = f0;
    out[b * 32 + 16 + l] = f1;
}

extern "C" void kernel_launch(void* const* d_in, const int* in_sizes, int n_in,
                              void* d_out, int out_size, void* d_ws, size_t ws_size,
                              hipStream_t stream) {
    const float* x       = (const float*)d_in[0];
    const float* table   = (const float*)d_in[1];
    const float* box_min = (const float*)d_in[2];
    const float* box_max = (const float*)d_in[3];
    float* out = (float*)d_out;

    const int B = in_sizes[0] / 3;
    const size_t ws_needed = (size_t)B * NLEV * sizeof(v2f);

    if (ws_size >= ws_needed && (B & 1) == 0) {
        const int chunks = (B + 511) / 512;       // per level, 512 pts/block
        const int gridA = 8 * 2 * chunks;         // 8 residues x 2 levels
        hipLaunchKernelGGL(ngp_levels_kernel, dim3(gridA), dim3(256), 0, stream,
                           x, table, box_min, box_max, (v2f*)d_ws, B, chunks);
        const int pairs = B / 2;
        const int gridB = (pairs + 255) / 256;
        hipLaunchKernelGGL(ngp_transpose_kernel, dim3(gridB), dim3(256), 0, stream,
                           (const v4f*)d_ws, out, B);
    } else {
        const int total = B * NLEV;
        const int blocks = (total + 255) / 256;
        hipLaunchKernelGGL(ngp_embed_fused_kernel, dim3(blocks), dim3(256), 0, stream,
                           x, table, box_min, box_max, out, B);
    }
}

// Round 5
// 378.795 us; speedup vs baseline: 1.4357x; 1.4357x over previous
//
#include <hip/hip_runtime.h>
#include <cstdint>

// Instant-NGP hash-grid embedder, 2-phase with level->XCD affinity.
//
// Phase A: one block = one level x 512 points, 2 pts/thread INTERLEAVED
//   (16 gathers in flight per thread — R2 showed A latency-bound at ~2.1
//   cyc/lane-gather with only 8 in flight). blockIdx%8 pins level pairs
//   (i, 15-i) to one XCD residue (verified R2: FETCH 1.56GB -> 149MB),
//   so each XCD's 4MB L2 holds the active level slab.
// Phase B: streaming transpose ws[l][b] -> out[b][f*16+l], exact R2 version.
//
// R4 LESSON: __builtin_nontemporal_* regressed BOTH phases (A 226->266,
// B 119->278) — no nt hints anywhere.
//
// Discrete steps (bottom_left trunc) replicated in float64 to match the
// NumPy reference under NEP-50 promotion. Resolutions hardcoded to the
// exact-math floor(16 * 2^(l/3)) values.

constexpr int NLEV = 16;
constexpr uint32_t HM_MASK = (1u << 19) - 1;

__device__ __constant__ double c_res[NLEV] = {
    16.0, 20.0, 25.0, 32.0, 40.0, 50.0, 64.0, 80.0,
    101.0, 128.0, 161.0, 203.0, 256.0, 322.0, 406.0, 512.0
};

// ---------------- Phase A: per-level gather+interp, level-major ws ----------
// Requires B % 512 == 0 (launcher guarantees; no bounds checks).
__global__ __launch_bounds__(256)
void ngp_levels_kernel(const float* __restrict__ x,
                       const float* __restrict__ table,
                       const float* __restrict__ box_min,
                       const float* __restrict__ box_max,
                       float2* __restrict__ ws,
                       int B, int chunks)
{
    // XCD-affinity: residue = blockIdx%8 -> XCD (HW round-robin dispatch).
    // XCD residue i: level i (phase 1, coarse) then 15-i (phase 2, fine).
    const int xcd = blockIdx.x & 7;
    const int s   = blockIdx.x >> 3;
    const int lev   = (s < chunks) ? xcd : (15 - xcd);
    const int chunk = (s < chunks) ? s : (s - chunks);
    const int b0 = chunk * 512 + threadIdx.x;   // 2 points/thread, 256 apart
    const int b1 = b0 + 256;

    const float bm0 = box_min[0], bm1 = box_min[1], bm2 = box_min[2];
    const float d0 = box_max[0] - bm0;
    const float d1 = box_max[1] - bm1;
    const float d2 = box_max[2] - bm2;
    const float2* __restrict__ tab2 = (const float2*)table;

    const double res = c_res[lev];
    const double g0 = (double)d0 / res;
    const double g1 = (double)d1 / res;
    const double g2 = (double)d2 / res;
    const uint32_t P1 = 2654435761u, P2 = 805459861u;
    const uint32_t base = (uint32_t)lev << 19;

    const int bp[2] = { b0, b1 };
    float w0[2], w1[2], w2[2];
    uint32_t idx[2][8];

    // ---- pass 1: addresses + weights for both points (straightline) ----
#pragma unroll
    for (int p = 0; p < 2; ++p) {
        const int b = bp[p];
        const float fx0 = x[3 * b + 0];
        const float fx1 = x[3 * b + 1];
        const float fx2 = x[3 * b + 2];
        const double q0 = (double)(fx0 - bm0) / g0;
        const double q1 = (double)(fx1 - bm1) / g1;
        const double q2 = (double)(fx2 - bm2) / g2;
        const int i0 = (int)q0;
        const int i1 = (int)q1;
        const int i2 = (int)q2;
        w0[p] = (float)(q0 - (double)i0);
        w1[p] = (float)(q1 - (double)i1);
        w2[p] = (float)(q2 - (double)i2);

        const uint32_t h0a = (uint32_t)i0;
        const uint32_t h0b = h0a + 1u;
        const uint32_t h1a = (uint32_t)i1 * P1;
        const uint32_t h1b = h1a + P1;
        const uint32_t h2a = (uint32_t)i2 * P2;
        const uint32_t h2b = h2a + P2;
        idx[p][0] = base + ((h0a ^ h1a ^ h2a) & HM_MASK);
        idx[p][1] = base + ((h0a ^ h1a ^ h2b) & HM_MASK);
        idx[p][2] = base + ((h0a ^ h1b ^ h2a) & HM_MASK);
        idx[p][3] = base + ((h0a ^ h1b ^ h2b) & HM_MASK);
        idx[p][4] = base + ((h0b ^ h1a ^ h2a) & HM_MASK);
        idx[p][5] = base + ((h0b ^ h1a ^ h2b) & HM_MASK);
        idx[p][6] = base + ((h0b ^ h1b ^ h2a) & HM_MASK);
        idx[p][7] = base + ((h0b ^ h1b ^ h2b) & HM_MASK);
    }

    // ---- pass 2: all 16 gathers issued back-to-back ----
    float2 v[2][8];
#pragma unroll
    for (int p = 0; p < 2; ++p)
#pragma unroll
        for (int c = 0; c < 8; ++c)
            v[p][c] = tab2[idx[p][c]];

    // ---- pass 3: interpolate + store ----
#pragma unroll
    for (int p = 0; p < 2; ++p) {
        const float u0 = 1.0f - w0[p], u1 = 1.0f - w1[p], u2 = 1.0f - w2[p];
        const float waa = u1 * u2;
        const float wab = u1 * w2[p];
        const float wba = w1[p] * u2;
        const float wbb = w1[p] * w2[p];
        const float f0 =
            u0 * (waa * v[p][0].x + wab * v[p][1].x + wba * v[p][2].x + wbb * v[p][3].x)
          + w0[p] * (waa * v[p][4].x + wab * v[p][5].x + wba * v[p][6].x + wbb * v[p][7].x);
        const float f1 =
            u0 * (waa * v[p][0].y + wab * v[p][1].y + wba * v[p][2].y + wbb * v[p][3].y)
          + w0[p] * (waa * v[p][4].y + wab * v[p][5].y + wba * v[p][6].y + wbb * v[p][7].y);
        ws[(size_t)lev * B + bp[p]] = make_float2(f0, f1);
    }
}

// ---------------- Phase B: transpose ws[l][b] -> out[b][f*16+l] -------------
// Exact R2 version (119 us known-good).
__global__ __launch_bounds__(256)
void ngp_transpose_kernel(const float2* __restrict__ ws,
                          float* __restrict__ out,
                          int B)
{
    const int b = blockIdx.x * 256 + threadIdx.x;
    if (b >= B) return;

    float2 v[NLEV];
#pragma unroll
    for (int l = 0; l < NLEV; ++l)
        v[l] = ws[(size_t)l * B + b];   // coalesced per level across the wave

    float4* __restrict__ o4 = (float4*)(out + (size_t)b * 32);
#pragma unroll
    for (int i = 0; i < 4; ++i)
        o4[i] = make_float4(v[4*i].x, v[4*i+1].x, v[4*i+2].x, v[4*i+3].x);
#pragma unroll
    for (int i = 0; i < 4; ++i)
        o4[4 + i] = make_float4(v[4*i].y, v[4*i+1].y, v[4*i+2].y, v[4*i+3].y);
}

// ---------------- Fallback: fused kernel (if ws too small / B%512!=0) -------
__global__ __launch_bounds__(256)
void ngp_embed_fused_kernel(const float* __restrict__ x,
                            const float* __restrict__ table,
                            const float* __restrict__ box_min,
                            const float* __restrict__ box_max,
                            float* __restrict__ out,
                            int B)
{
    const int gid = blockIdx.x * 256 + threadIdx.x;
    const int b = gid >> 4;
    const int l = gid & 15;
    if (b >= B) return;

    const float bm0 = box_min[0], bm1 = box_min[1], bm2 = box_min[2];
    const float d0 = box_max[0] - bm0;
    const float d1 = box_max[1] - bm1;
    const float d2 = box_max[2] - bm2;

    const float fx0 = x[3 * b + 0];
    const float fx1 = x[3 * b + 1];
    const float fx2 = x[3 * b + 2];
    const double res = c_res[l];
    const double q0 = (double)(fx0 - bm0) / ((double)d0 / res);
    const double q1 = (double)(fx1 - bm1) / ((double)d1 / res);
    const double q2 = (double)(fx2 - bm2) / ((double)d2 / res);
    const int i0 = (int)q0;
    const int i1 = (int)q1;
    const int i2 = (int)q2;
    const float w0 = (float)(q0 - (double)i0);
    const float w1 = (float)(q1 - (double)i1);
    const float w2 = (float)(q2 - (double)i2);

    const uint32_t P1 = 2654435761u, P2 = 805459861u;
    const uint32_t h0a = (uint32_t)i0, h0b = h0a + 1u;
    const uint32_t h1a = (uint32_t)i1 * P1, h1b = h1a + P1;
    const uint32_t h2a = (uint32_t)i2 * P2, h2b = h2a + P2;
    const uint32_t base = (uint32_t)l << 19;
    const float2* tab2 = (const float2*)table;

    const float2 v000 = tab2[base + ((h0a ^ h1a ^ h2a) & HM_MASK)];
    const float2 v001 = tab2[base + ((h0a ^ h1a ^ h2b) & HM_MASK)];
    const float2 v010 = tab2[base + ((h0a ^ h1b ^ h2a) & HM_MASK)];
    const float2 v011 = tab2[base + ((h0a ^ h1b ^ h2b) & HM_MASK)];
    const float2 v100 = tab2[base + ((h0b ^ h1a ^ h2a) & HM_MASK)];
    const float2 v101 = tab2[base + ((h0b ^ h1a ^ h2b) & HM_MASK)];
    const float2 v110 = tab2[base + ((h0b ^ h1b ^ h2a) & HM_MASK)];
    const float2 v111 = tab2[base + ((h0b ^ h1b ^ h2b) & HM_MASK)];

    const float u0 = 1.0f - w0, u1 = 1.0f - w1, u2 = 1.0f - w2;
    const float waa = u1 * u2, wab = u1 * w2, wba = w1 * u2, wbb = w1 * w2;
    const float f0 = u0 * (waa * v000.x + wab * v001.x + wba * v010.x + wbb * v011.x)
                   + w0 * (waa * v100.x + wab * v101.x + wba * v110.x + wbb * v111.x);
    const float f1 = u0 * (waa * v000.y + wab * v001.y + wba * v010.y + wbb * v011.y)
                   + w0 * (waa * v100.y + wab * v101.y + wba * v110.y + wbb * v111.y);

    out[b * 32 + l]      = f0;
    out[b * 32 + 16 + l] = f1;
}

extern "C" void kernel_launch(void* const* d_in, const int* in_sizes, int n_in,
                              void* d_out, int out_size, void* d_ws, size_t ws_size,
                              hipStream_t stream) {
    const float* x       = (const float*)d_in[0];
    const float* table   = (const float*)d_in[1];
    const float* box_min = (const float*)d_in[2];
    const float* box_max = (const float*)d_in[3];
    float* out = (float*)d_out;

    const int B = in_sizes[0] / 3;
    const size_t ws_needed = (size_t)B * NLEV * sizeof(float2);

    if (ws_size >= ws_needed && (B % 512) == 0) {
        const int chunks = B / 512;               // per level, 512 pts/block
        const int gridA = 8 * 2 * chunks;         // 8 residues x 2 levels
        hipLaunchKernelGGL(ngp_levels_kernel, dim3(gridA), dim3(256), 0, stream,
                           x, table, box_min, box_max, (float2*)d_ws, B, chunks);
        const int gridB = (B + 255) / 256;
        hipLaunchKernelGGL(ngp_transpose_kernel, dim3(gridB), dim3(256), 0, stream,
                           (const float2*)d_ws, out, B);
    } else {
        const int total = B * NLEV;
        const int blocks = (total + 255) / 256;
        hipLaunchKernelGGL(ngp_embed_fused_kernel, dim3(blocks), dim3(256), 0, stream,
                           x, table, box_min, box_max, out, B);
    }
}

// Round 6
// 334.038 us; speedup vs baseline: 1.6280x; 1.1340x over previous
//
#include <hip/hip_runtime.h>
#include <cstdint>

// Instant-NGP hash-grid embedder, 2-phase with level->XCD affinity.
//
// Phase A (EXACT R2 form — 226us measured): one block = one level x 256
//   points, 1 pt/thread. blockIdx%8 pins level pairs (i, 15-i) to one XCD
//   residue (verified R2: FETCH 1.56GB -> 149MB). Phase A sits at ~97% of
//   the per-XCD L2 request-throughput roofline (8.4M random 8B gathers/XCD
//   / 16 ch / 2.4GHz = 218us) — R5 showed more per-thread MLP does NOT help.
// Phase B: LDS tile transpose. R2-form B spent 115us at 1.2TB/s because
//   each out-store instr wrote 64x16B at 128B stride (4 instrs per 64B
//   line). Now: coalesced ws loads -> padded LDS (rows=2l+f, stride 257
//   floats; <=2-way banks = free) -> store instrs write 1KB contiguous.
//
// R4 LESSON: no __builtin_nontemporal_* anywhere (regressed both phases).
// R5 LESSON: phase A is L2-request-bound, not latency-bound.
//
// Discrete steps (bottom_left trunc) replicated in float64 to match the
// NumPy reference under NEP-50 promotion. Resolutions hardcoded to the
// exact-math floor(16 * 2^(l/3)) values.

constexpr int NLEV = 16;
constexpr uint32_t HM_MASK = (1u << 19) - 1;

__device__ __constant__ double c_res[NLEV] = {
    16.0, 20.0, 25.0, 32.0, 40.0, 50.0, 64.0, 80.0,
    101.0, 128.0, 161.0, 203.0, 256.0, 322.0, 406.0, 512.0
};

__device__ __forceinline__ void ngp_eval_point(
    int b, int lev,
    const float* __restrict__ x,
    const float2* __restrict__ tab2,
    float bm0, float bm1, float bm2,
    float d0, float d1, float d2,
    float& f0, float& f1)
{
    const float fx0 = x[3 * b + 0];
    const float fx1 = x[3 * b + 1];
    const float fx2 = x[3 * b + 2];

    const double res = c_res[lev];
    const double g0 = (double)d0 / res;
    const double g1 = (double)d1 / res;
    const double g2 = (double)d2 / res;
    const double q0 = (double)(fx0 - bm0) / g0;
    const double q1 = (double)(fx1 - bm1) / g1;
    const double q2 = (double)(fx2 - bm2) / g2;
    const int i0 = (int)q0;
    const int i1 = (int)q1;
    const int i2 = (int)q2;
    const float w0 = (float)(q0 - (double)i0);
    const float w1 = (float)(q1 - (double)i1);
    const float w2 = (float)(q2 - (double)i2);

    const uint32_t P1 = 2654435761u, P2 = 805459861u;
    const uint32_t h0a = (uint32_t)i0;
    const uint32_t h0b = h0a + 1u;
    const uint32_t h1a = (uint32_t)i1 * P1;
    const uint32_t h1b = h1a + P1;
    const uint32_t h2a = (uint32_t)i2 * P2;
    const uint32_t h2b = h2a + P2;
    const uint32_t base = (uint32_t)lev << 19;

    const float2 v000 = tab2[base + ((h0a ^ h1a ^ h2a) & HM_MASK)];
    const float2 v001 = tab2[base + ((h0a ^ h1a ^ h2b) & HM_MASK)];
    const float2 v010 = tab2[base + ((h0a ^ h1b ^ h2a) & HM_MASK)];
    const float2 v011 = tab2[base + ((h0a ^ h1b ^ h2b) & HM_MASK)];
    const float2 v100 = tab2[base + ((h0b ^ h1a ^ h2a) & HM_MASK)];
    const float2 v101 = tab2[base + ((h0b ^ h1a ^ h2b) & HM_MASK)];
    const float2 v110 = tab2[base + ((h0b ^ h1b ^ h2a) & HM_MASK)];
    const float2 v111 = tab2[base + ((h0b ^ h1b ^ h2b) & HM_MASK)];

    const float u0 = 1.0f - w0, u1 = 1.0f - w1, u2 = 1.0f - w2;
    const float waa = u1 * u2;
    const float wab = u1 * w2;
    const float wba = w1 * u2;
    const float wbb = w1 * w2;

    f0 = u0 * (waa * v000.x + wab * v001.x + wba * v010.x + wbb * v011.x)
       + w0 * (waa * v100.x + wab * v101.x + wba * v110.x + wbb * v111.x);
    f1 = u0 * (waa * v000.y + wab * v001.y + wba * v010.y + wbb * v011.y)
       + w0 * (waa * v100.y + wab * v101.y + wba * v110.y + wbb * v111.y);
}

// ---------------- Phase A: per-level gather+interp, level-major ws ----------
// EXACT R2 structure (measured 226us).
__global__ __launch_bounds__(256)
void ngp_levels_kernel(const float* __restrict__ x,
                       const float* __restrict__ table,
                       const float* __restrict__ box_min,
                       const float* __restrict__ box_max,
                       float2* __restrict__ ws,
                       int B, int chunks)
{
    // XCD-affinity: residue = blockIdx%8 -> XCD (HW round-robin dispatch).
    // XCD residue i: level i (phase 1, coarse) then 15-i (phase 2, fine).
    const int xcd = blockIdx.x & 7;
    const int s   = blockIdx.x >> 3;
    const int lev   = (s < chunks) ? xcd : (15 - xcd);
    const int chunk = (s < chunks) ? s : (s - chunks);
    const int b = chunk * 256 + threadIdx.x;
    if (b >= B) return;

    const float bm0 = box_min[0], bm1 = box_min[1], bm2 = box_min[2];
    const float d0 = box_max[0] - bm0;
    const float d1 = box_max[1] - bm1;
    const float d2 = box_max[2] - bm2;

    float f0, f1;
    ngp_eval_point(b, lev, x, (const float2*)table,
                   bm0, bm1, bm2, d0, d1, d2, f0, f1);

    ws[(size_t)lev * B + b] = make_float2(f0, f1);  // coalesced 8B
}

// ---------------- Phase B: LDS tile transpose ws[l][b] -> out[b][f*16+l] ----
// Block = 256 points. Requires B % 256 == 0.
// LDS layout: float rows indexed r = 2*l + f, row stride 257 floats (pad
// breaks the 32-point bank alias in stage 2). Size = 32*257*4 = 32896 B.
constexpr int LDS_STRIDE = 257;

__global__ __launch_bounds__(256)
void ngp_transpose_kernel(const float2* __restrict__ ws,
                          float* __restrict__ out,
                          int B)
{
    __shared__ float lds[32 * LDS_STRIDE];

    const int t  = threadIdx.x;
    const int P0 = blockIdx.x * 256;

    // Stage 1: coalesced level-row loads (512B per wave-instr) -> LDS.
    // Bank: ((2l*257 + t)) % 32 = (2l + t) % 32 -> 2 lanes/bank (free).
#pragma unroll
    for (int l = 0; l < NLEV; ++l) {
        const float2 v = ws[(size_t)l * B + P0 + t];
        lds[(2 * l)     * LDS_STRIDE + t] = v.x;
        lds[(2 * l + 1) * LDS_STRIDE + t] = v.y;
    }
    __syncthreads();

    // Stage 2: each store instr writes 1KB fully contiguous.
    // Lane t, iter j covers out flat range [P0*32 + j*1024 + 4t, +4):
    //   point p = j*32 + (t>>3), f = (t>>2)&1, l = (t&3)*4 + k.
    const int p_lo = t >> 3;
    const int f    = (t >> 2) & 1;
    const int l0   = (t & 3) * 4;
#pragma unroll
    for (int j = 0; j < 8; ++j) {
        const int p = j * 32 + p_lo;
        float4 v;
        v.x = lds[(2 * (l0 + 0) + f) * LDS_STRIDE + p];
        v.y = lds[(2 * (l0 + 1) + f) * LDS_STRIDE + p];
        v.z = lds[(2 * (l0 + 2) + f) * LDS_STRIDE + p];
        v.w = lds[(2 * (l0 + 3) + f) * LDS_STRIDE + p];
        *(float4*)(out + (size_t)P0 * 32 + j * 1024 + t * 4) = v;
    }
}

// ---------------- Fallback: fused kernel (if ws too small / B%256!=0) -------
__global__ __launch_bounds__(256)
void ngp_embed_fused_kernel(const float* __restrict__ x,
                            const float* __restrict__ table,
                            const float* __restrict__ box_min,
                            const float* __restrict__ box_max,
                            float* __restrict__ out,
                            int B)
{
    const int gid = blockIdx.x * 256 + threadIdx.x;
    const int b = gid >> 4;
    const int l = gid & 15;
    if (b >= B) return;

    const float bm0 = box_min[0], bm1 = box_min[1], bm2 = box_min[2];
    const float d0 = box_max[0] - bm0;
    const float d1 = box_max[1] - bm1;
    const float d2 = box_max[2] - bm2;

    float f0, f1;
    ngp_eval_point(b, l, x, (const float2*)table,
                   bm0, bm1, bm2, d0, d1, d2, f0, f1);

    out[b * 32 + l]      = f0;
    out[b * 32 + 16 + l] = f1;
}

extern "C" void kernel_launch(void* const* d_in, const int* in_sizes, int n_in,
                              void* d_out, int out_size, void* d_ws, size_t ws_size,
                              hipStream_t stream) {
    const float* x       = (const float*)d_in[0];
    const float* table   = (const float*)d_in[1];
    const float* box_min = (const float*)d_in[2];
    const float* box_max = (const float*)d_in[3];
    float* out = (float*)d_out;

    const int B = in_sizes[0] / 3;
    const size_t ws_needed = (size_t)B * NLEV * sizeof(float2);

    if (ws_size >= ws_needed && (B % 256) == 0) {
        const int chunks = B / 256;               // per level, 256 pts/block
        const int gridA = 8 * 2 * chunks;         // 8 residues x 2 levels
        hipLaunchKernelGGL(ngp_levels_kernel, dim3(gridA), dim3(256), 0, stream,
                           x, table, box_min, box_max, (float2*)d_ws, B, chunks);
        const int gridB = B / 256;
        hipLaunchKernelGGL(ngp_transpose_kernel, dim3(gridB), dim3(256), 0, stream,
                           (const float2*)d_ws, out, B);
    } else {
        const int total = B * NLEV;
        const int blocks = (total + 255) / 256;
        hipLaunchKernelGGL(ngp_embed_fused_kernel, dim3(blocks), dim3(256), 0, stream,
                           x, table, box_min, box_max, out, B);
    }
}